// Round 17
// baseline (4189.377 us; speedup 1.0000x reference)
//
#include <hip/hip_runtime.h>
#include <math.h>

#define NN 65536
#define TWO_N (2 * NN)
#define VOCAB 1000
#define MD 256
#define G3 768
#define DMAX 65536
#define DCAP 128
#define NB 4
#define NT 256
#define NGRP 32
#define NSPAN 1024
#define SPAN 128
#define SLOTSTRIDE 16
#define MAXBLK 2048

struct Params {
    const int* l_tokens; const int* l_parent;
    const int* r_tokens; const int* r_parent;
    const float* emb_W;
    const float* Wioux; const float* bioux;
    const float* Wiouh; const float* biouh;
    const float* Wfx;   const float* bfx;
    const float* Wfh;   const float* bfh;
    const float* Wh;    const float* bh;
    const float* Wp;    const float* bp;
    float* out;
    // workspace
    float* E_ioux;   // [VOCAB][768]
    float* E_fx;     // [VOCAB][256]
    unsigned int* Wiouh_p;  // [128][768] packed bf16 pairs (k,k+1)
    unsigned int* Wfh_p;    // [128][256] packed bf16 pairs
    float* h_sum;    // [cap_rows][256]
    float* fc_sum;   // [cap_rows][256]
    float* c_root;   // [2][256]
    int* anc_a; int* anc_b; int* dep_a; int* dep_b;  // [2N] (b aliased)
    int* hc;                                          // [2N]
    int* pending;                                     // [2N] dataflow counters
    int* rank;                                        // [2N]
    int* blocksum;                                    // [NSPAN]
    int* cnt; int* offs; int* cur;                    // [2*DMAX]
    int* order;                                        // [2N]
    int* gtab;                                         // flat group table
    int* dbase;                                        // [DMAX] per-depth group base
    int* maxd;   // [0..1]=maxd, +2 flags, 20=mode, 21=Itot, 22=GT
    int* bar;
    int cap_rows;
};

union SMem {
    struct { float es[4][MD]; } e;
    struct {
        float hls[NB][MD];
        int nid[NB]; int row[NB]; int prow[NB]; int tok[NB]; int ptok[NB];
        int pgid[NB];
    } w;
    struct { int hcnt[2 * DCAP]; int hbase[2 * DCAP]; int hmax2[2]; } s;
    struct { float vec[2 * MD]; float red[2][NT]; } h;
};

__device__ __forceinline__ float sigmoidf_(float x) {
    return 1.0f / (1.0f + __expf(-x));
}
__device__ __forceinline__ float tanhf_(float x) {
    float ex = __expf(2.0f * x);
    return 1.0f - 2.0f / (ex + 1.0f);
}
__device__ __forceinline__ unsigned int bf16rne_(float x) {
    unsigned int b = __float_as_uint(x);
    return (b + 0x7FFFu + ((b >> 16) & 1u)) >> 16;
}
__device__ __forceinline__ float bflo_(unsigned int w) {
    return __uint_as_float(w << 16);
}
__device__ __forceinline__ float bfhi_(unsigned int w) {
    return __uint_as_float(w & 0xFFFF0000u);
}

__device__ __forceinline__ int aload_(int* p) {
    return __hip_atomic_load(p, __ATOMIC_RELAXED, __HIP_MEMORY_SCOPE_AGENT);
}
// coherence-point float load (bypasses potentially-stale L1/L2) for dataflow
__device__ __forceinline__ float loadf_coh(const float* p, int df) {
    if (df) return __hip_atomic_load((float*)p, __ATOMIC_RELAXED,
                                     __HIP_MEMORY_SCOPE_AGENT);
    return *p;
}

// ---- slot barrier: store arrivals, block-0 sweep, group release ----
__device__ void gbarrier(int* bar, int bid, int nblk, int gsz, int ep, int t) {
    __syncthreads();
    int* relw = bar + MAXBLK * SLOTSTRIDE;
    if (t == 0) {
        __builtin_amdgcn_fence(__ATOMIC_RELEASE, "agent");
        __hip_atomic_store(bar + bid * SLOTSTRIDE, ep, __ATOMIC_RELAXED,
                           __HIP_MEMORY_SCOPE_AGENT);
    }
    if (bid == 0) {
        for (int s = t; s < nblk; s += NT) {
            while (aload_(bar + s * SLOTSTRIDE) < ep) __builtin_amdgcn_s_sleep(1);
        }
        __builtin_amdgcn_fence(__ATOMIC_ACQUIRE, "agent");
        __syncthreads();
        if (t < NGRP) {
            __builtin_amdgcn_fence(__ATOMIC_RELEASE, "agent");
            __hip_atomic_store(relw + t * 32, ep, __ATOMIC_RELAXED,
                               __HIP_MEMORY_SCOPE_AGENT);
        }
    } else {
        if (t == 0) {
            int g = bid / gsz; if (g >= NGRP) g = NGRP - 1;
            while (aload_(relw + g * 32) < ep) __builtin_amdgcn_s_sleep(2);
            __builtin_amdgcn_fence(__ATOMIC_ACQUIRE, "agent");
        }
    }
    __syncthreads();
}

// processes NB nodes of ONE tree; df=1 -> dataflow (spin on pending, bypass state loads)
__device__ void process_group(const Params& P, SMem& sm, int base, int cntv,
                              int t, int rowbase, int df) {
    __syncthreads();
    if (t < NB) {
        int g = -1, row = -1, prow = 0, tok = 0, ptok = 0, pgid = 0;
        if (t < cntv) {
            g = P.order[base + t];
            int tree = g >> 16, i = g & (NN - 1);
            const int* toks = tree ? P.r_tokens : P.l_tokens;
            const int* pars = tree ? P.r_parent : P.l_parent;
            tok = toks[i];
            int pl = pars[i];
            ptok = toks[pl];
            pgid = (tree << 16) | pl;
            if (P.hc[g]) row = P.rank[g] - rowbase;      // leaf -> -1 (zero state)
            prow = P.rank[pgid] - rowbase;               // parent always internal
        }
        sm.w.nid[t] = g; sm.w.row[t] = row; sm.w.prow[t] = prow;
        sm.w.tok[t] = tok; sm.w.ptok[t] = ptok; sm.w.pgid[t] = pgid;
        if (df && g >= 0) {
            while (aload_(&P.pending[g]) != 0) __builtin_amdgcn_s_sleep(4);
        }
    }
    __syncthreads();
    #pragma unroll
    for (int nb = 0; nb < NB; ++nb) {
        int r = sm.w.row[nb];
        sm.w.hls[nb][t] = (r >= 0)
            ? loadf_coh(&P.h_sum[(size_t)r * MD + t], df) : 0.0f;
    }
    __syncthreads();

    // ---- iou = E_ioux[tok] + h_sum @ Wiouh + biouh (bf16 weights) ----
    float ai[NB], ao[NB], au[NB];
    #pragma unroll
    for (int nb = 0; nb < NB; ++nb) { ai[nb] = 0.f; ao[nb] = 0.f; au[nb] = 0.f; }
    const unsigned int* Wp = P.Wiouh_p;
    #pragma unroll 2
    for (int k = 0; k < MD; k += 4) {
        int r0 = (k >> 1) * G3 + t;
        unsigned int a01 = Wp[r0],       a23 = Wp[r0 + G3];
        unsigned int b01 = Wp[r0 + 256], b23 = Wp[r0 + G3 + 256];
        unsigned int c01 = Wp[r0 + 512], c23 = Wp[r0 + G3 + 512];
        float wi0 = bflo_(a01), wi1 = bfhi_(a01), wi2 = bflo_(a23), wi3 = bfhi_(a23);
        float wo0 = bflo_(b01), wo1 = bfhi_(b01), wo2 = bflo_(b23), wo3 = bfhi_(b23);
        float wu0 = bflo_(c01), wu1 = bfhi_(c01), wu2 = bflo_(c23), wu3 = bfhi_(c23);
        #pragma unroll
        for (int nb = 0; nb < NB; ++nb) {
            float4 hv = *(const float4*)&sm.w.hls[nb][k];
            ai[nb] += wi0 * hv.x; ai[nb] += wi1 * hv.y; ai[nb] += wi2 * hv.z; ai[nb] += wi3 * hv.w;
            ao[nb] += wo0 * hv.x; ao[nb] += wo1 * hv.y; ao[nb] += wo2 * hv.z; ao[nb] += wo3 * hv.w;
            au[nb] += wu0 * hv.x; au[nb] += wu1 * hv.y; au[nb] += wu2 * hv.z; au[nb] += wu3 * hv.w;
        }
    }

    // ---- gates, c, h ----
    float cv[NB];
    float b_i = P.biouh[t], b_o = P.biouh[256 + t], b_u = P.biouh[512 + t];
    __syncthreads();
    #pragma unroll
    for (int nb = 0; nb < NB; ++nb) {
        int g = sm.w.nid[nb];
        float hval = 0.0f, cval = 0.0f;
        if (g >= 0) {
            const float* Ei = P.E_ioux + (size_t)sm.w.tok[nb] * G3;
            float ig = Ei[t] + ai[nb] + b_i;
            float og = Ei[256 + t] + ao[nb] + b_o;
            float ug = Ei[512 + t] + au[nb] + b_u;
            int r = sm.w.row[nb];
            float fcv = (r >= 0)
                ? loadf_coh(&P.fc_sum[(size_t)r * MD + t], df) : 0.0f;
            cval = sigmoidf_(ig) * tanhf_(ug) + fcv;
            hval = sigmoidf_(og) * tanhf_(cval);
        }
        cv[nb] = cval;
        sm.w.hls[nb][t] = hval;
    }
    __syncthreads();

    // ---- f = sigmoid(h @ Wfh + bfh + E_fx[ptok]) ; scatter to parent ----
    float af[NB];
    #pragma unroll
    for (int nb = 0; nb < NB; ++nb) af[nb] = 0.f;
    const unsigned int* Wfp = P.Wfh_p;
    #pragma unroll 2
    for (int k = 0; k < MD; k += 4) {
        int r0 = (k >> 1) * MD + t;
        unsigned int f01 = Wfp[r0], f23 = Wfp[r0 + MD];
        float wf0 = bflo_(f01), wf1 = bfhi_(f01), wf2 = bflo_(f23), wf3 = bfhi_(f23);
        #pragma unroll
        for (int nb = 0; nb < NB; ++nb) {
            float4 hv = *(const float4*)&sm.w.hls[nb][k];
            af[nb] += wf0 * hv.x; af[nb] += wf1 * hv.y; af[nb] += wf2 * hv.z; af[nb] += wf3 * hv.w;
        }
    }
    float b_f = P.bfh[t];
    #pragma unroll
    for (int nb = 0; nb < NB; ++nb) {
        int g = sm.w.nid[nb];
        if (g < 0) continue;
        int i = g & (NN - 1);
        if (i == 0) {
            P.c_root[(g >> 16) * MD + t] = cv[nb];
        } else {
            float f = sigmoidf_(af[nb] + b_f + P.E_fx[(size_t)sm.w.ptok[nb] * MD + t]);
            int p = sm.w.prow[nb];
            atomicAdd(&P.h_sum[(size_t)p * MD + t], sm.w.hls[nb][t]);
            atomicAdd(&P.fc_sum[(size_t)p * MD + t], f * cv[nb]);
        }
    }
    if (df) {
        __syncthreads();   // drains every wave's vmcnt -> all atomics complete
        if (t < NB) {
            int g = sm.w.nid[t];
            if (g >= 0 && (g & (NN - 1)) != 0) {
                __builtin_amdgcn_fence(__ATOMIC_RELEASE, "agent");
                __hip_atomic_fetch_add(&P.pending[sm.w.pgid[t]], -1,
                                       __ATOMIC_RELAXED, __HIP_MEMORY_SCOPE_AGENT);
            }
        }
    }
}

__device__ void etab_body(const Params& P, SMem& sm, int t, int bid, int nblk) {
    for (int v0 = bid * 4; v0 < VOCAB; v0 += nblk * 4) {
        __syncthreads();
        #pragma unroll
        for (int r = 0; r < 4; ++r)
            sm.e.es[r][t] = (v0 + r < VOCAB) ? P.emb_W[(size_t)(v0 + r) * MD + t] : 0.f;
        __syncthreads();
        float a0[4] = {0.f,0.f,0.f,0.f}, a1[4] = {0.f,0.f,0.f,0.f};
        float a2[4] = {0.f,0.f,0.f,0.f}, a3[4] = {0.f,0.f,0.f,0.f};
        for (int k = 0; k < MD; ++k) {
            float wi = P.Wioux[k * G3 + t];
            float wo = P.Wioux[k * G3 + 256 + t];
            float wu = P.Wioux[k * G3 + 512 + t];
            float wf = P.Wfx[k * MD + t];
            #pragma unroll
            for (int r = 0; r < 4; ++r) {
                float e = sm.e.es[r][k];
                a0[r] += wi * e; a1[r] += wo * e; a2[r] += wu * e; a3[r] += wf * e;
            }
        }
        float bi = P.bioux[t], bo = P.bioux[256 + t], bu = P.bioux[512 + t], bf = P.bfx[t];
        for (int r = 0; r < 4; ++r) {
            if (v0 + r < VOCAB) {
                P.E_ioux[(size_t)(v0 + r) * G3 + t]       = a0[r] + bi;
                P.E_ioux[(size_t)(v0 + r) * G3 + 256 + t] = a1[r] + bo;
                P.E_ioux[(size_t)(v0 + r) * G3 + 512 + t] = a2[r] + bu;
                P.E_fx[(size_t)(v0 + r) * MD + t]         = a3[r] + bf;
            }
        }
        __syncthreads();
    }
}

__device__ void head_body(const Params& P, SMem& sm, int t) {
    float cl = P.c_root[t], cr = P.c_root[MD + t];
    sm.h.vec[t] = cl * cr;
    sm.h.vec[MD + t] = fabsf(cl - cr);
    __syncthreads();
    float acc = 0.f;
    for (int j = 0; j < 2 * MD; ++j) acc += sm.h.vec[j] * P.Wh[(size_t)j * MD + t];
    float hid = sigmoidf_(acc + P.bh[t]);
    sm.h.red[0][t] = hid * P.Wp[t * 2 + 0];
    sm.h.red[1][t] = hid * P.Wp[t * 2 + 1];
    __syncthreads();
    for (int s = 128; s > 0; s >>= 1) {
        if (t < s) {
            sm.h.red[0][t] += sm.h.red[0][t + s];
            sm.h.red[1][t] += sm.h.red[1][t + s];
        }
        __syncthreads();
    }
    if (t == 0) {
        float l0 = sm.h.red[0][0] + P.bp[0];
        float l1 = sm.h.red[1][0] + P.bp[1];
        float mx = fmaxf(l0, l1);
        float e0 = __expf(l0 - mx), e1 = __expf(l1 - mx);
        float inv = 1.0f / (e0 + e1);
        P.out[0] = e0 * inv;
        P.out[1] = e1 * inv;
    }
}

// =======================================================================
// Persistent fused kernel: dataflow ladder, fine-grained groups (NB=4)
// to shorten the per-level critical path.
// =======================================================================
__global__ __launch_bounds__(NT, 4) void fused_kernel(Params P) {
    __shared__ SMem sm;
    const int t = threadIdx.x;
    const int bid = blockIdx.x;
    const int nblk = gridDim.x;
    const int gsz = nblk / NGRP;
    const int gsize = nblk * NT;
    const int gtid = bid * NT + t;
    int* flags = P.maxd + 2;
    int ep = 0;

    // ---- A0: zero flags/counters/hc/pending + weight compress + E tables ----
    for (int i = gtid; i < TWO_N; i += gsize) { P.hc[i] = 0; P.pending[i] = 0; }
    for (int i = gtid; i < 2 * DMAX; i += gsize) { P.cnt[i] = 0; P.cur[i] = 0; }
    if (gtid < 2) P.maxd[gtid] = 0;
    if (gtid >= 2 && gtid < 24) flags[gtid - 2] = 0;
    for (int i = gtid; i < (MD / 2) * G3; i += gsize) {
        int kk = i / G3, n = i - kk * G3;
        float x0 = P.Wiouh[(size_t)(2 * kk) * G3 + n];
        float x1 = P.Wiouh[(size_t)(2 * kk + 1) * G3 + n];
        P.Wiouh_p[i] = bf16rne_(x0) | (bf16rne_(x1) << 16);
    }
    for (int i = gtid; i < (MD / 2) * MD; i += gsize) {
        int kk = i >> 8, n = i & (MD - 1);
        float x0 = P.Wfh[(size_t)(2 * kk) * MD + n];
        float x1 = P.Wfh[(size_t)(2 * kk + 1) * MD + n];
        P.Wfh_p[i] = bf16rne_(x0) | (bf16rne_(x1) << 16);
    }
    etab_body(P, sm, t, bid, nblk);
    gbarrier(P.bar, bid, nblk, gsz, ++ep, t);

    // ---- A1: anc/dep init + has-child flags + child counts ----
    for (int g = gtid; g < TWO_N; g += gsize) {
        int tree = g >> 16, i = g & (NN - 1);
        if (i == 0) { P.anc_a[g] = g; P.dep_a[g] = 0; }
        else {
            const int* par = tree ? P.r_parent : P.l_parent;
            int pg = (tree << 16) | par[i];
            P.anc_a[g] = pg;
            P.dep_a[g] = 1;
            P.hc[pg] = 1;
            atomicAdd(&P.pending[pg], 1);
        }
    }
    gbarrier(P.bar, bid, nblk, gsz, ++ep, t);

    // ---- C: pointer doubling with early exit ----
    {
        int* pa = P.anc_a; int* pd = P.dep_a; int* qa = P.anc_b; int* qd = P.dep_b;
        for (int it = 0; it < 16; ++it) {
            int changed = 0;
            for (int g = gtid; g < TWO_N; g += gsize) {
                int a = pa[g];
                int da = pd[a];
                qd[g] = pd[g] + da;
                qa[g] = pa[a];
                changed |= (da != 0);
            }
            if (changed) flags[it] = 1;
            gbarrier(P.bar, bid, nblk, gsz, ++ep, t);
            int* tmp = pa; pa = qa; qa = tmp;
            tmp = pd; pd = qd; qd = tmp;
            if (flags[it] == 0) break;
        }
        if (pd != P.dep_a) {
            for (int g = gtid; g < TWO_N; g += gsize) P.dep_a[g] = pd[g];
            gbarrier(P.bar, bid, nblk, gsz, ++ep, t);
        }
    }

    // ---- S1: depth hist + per-span hc sums ----
    {
        for (int i = t; i < 2 * DCAP; i += NT) sm.s.hcnt[i] = 0;
        if (t < 2) sm.s.hmax2[t] = 0;
        __syncthreads();
        for (int g = gtid; g < TWO_N; g += gsize) {
            int tree = g >> 16;
            int d = P.dep_a[g];
            if (d < DCAP) {
                atomicAdd(&sm.s.hcnt[tree * DCAP + d], 1);
                atomicMax(&sm.s.hmax2[tree], d);
            } else {
                atomicAdd(&P.cnt[tree * DMAX + d], 1);
                atomicMax(&P.maxd[tree], d);
            }
        }
        __syncthreads();
        for (int i = t; i < 2 * DCAP; i += NT) {
            int c = sm.s.hcnt[i];
            if (c > 0) atomicAdd(&P.cnt[(i >= DCAP ? DMAX : 0) + (i & (DCAP - 1))], c);
        }
        if (t < 2) atomicMax(&P.maxd[t], sm.s.hmax2[t]);
        for (int sp = bid; sp < NSPAN; sp += nblk) {
            __syncthreads();
            if (t == 0) sm.s.hbase[0] = 0;
            __syncthreads();
            if (t < SPAN && P.hc[sp * SPAN + t]) atomicAdd(&sm.s.hbase[0], 1);
            __syncthreads();
            if (t == 0) P.blocksum[sp] = sm.s.hbase[0];
        }
    }
    gbarrier(P.bar, bid, nblk, gsz, ++ep, t);

    // ---- S2 (block 0): scans; Itot; mode; offs prefix; group table ----
    if (bid == 0) {
        int4 v = ((const int4*)P.blocksum)[t];
        int s = v.x + v.y + v.z + v.w;
        sm.s.hcnt[t] = s;
        __syncthreads();
        for (int off = 1; off < NT; off <<= 1) {
            int a = (t >= off) ? sm.s.hcnt[t - off] : 0;
            __syncthreads();
            sm.s.hcnt[t] += a;
            __syncthreads();
        }
        int excl = t ? sm.s.hcnt[t - 1] : 0;
        int4 r;
        r.x = excl; r.y = r.x + v.x; r.z = r.y + v.y; r.w = r.z + v.z;
        ((int4*)P.blocksum)[t] = r;
        if (t == NT - 1) {
            int itot = sm.s.hcnt[NT - 1];
            P.maxd[21] = itot;
            P.maxd[20] = (itot <= P.cap_rows) ? 1 : 0;
        }
        __syncthreads();
        if (t < 2) {
            int tree = t;
            int run = tree * NN;
            int md = P.maxd[tree];
            for (int d = 0; d <= md; ++d) {
                P.offs[tree * DMAX + d] = run;
                run += P.cnt[tree * DMAX + d];
            }
        }
        __syncthreads();
        int md0 = P.maxd[0], md1 = P.maxd[1];
        int md = md0 > md1 ? md0 : md1;
        if (t == 0) {
            int j = 0;
            for (int d = md; d >= 0; --d) {
                P.dbase[d] = j;
                int n0 = (d <= md0) ? P.cnt[d] : 0;
                int n1 = (d <= md1) ? P.cnt[DMAX + d] : 0;
                j += (n0 + NB - 1) / NB + (n1 + NB - 1) / NB;
            }
            P.maxd[22] = j;   // GT
        }
        __syncthreads();
        for (int d = t; d <= md; d += NT) {
            int j = P.dbase[d];
            for (int tr = 0; tr < 2; ++tr) {
                int mdt = tr ? md1 : md0;
                int n = (d <= mdt) ? P.cnt[tr * DMAX + d] : 0;
                int st = P.offs[tr * DMAX + d];
                for (int b = 0; b < n; b += NB) {
                    int cv = n - b; if (cv > NB) cv = NB;
                    P.gtab[j++] = (st + b) | (cv << 20);
                }
            }
        }
    }
    gbarrier(P.bar, bid, nblk, gsz, ++ep, t);

    int mode = P.maxd[20];
    int itot = P.maxd[21];
    int i0 = P.blocksum[NSPAN / 2];

    // ---- S3: rank writes + state zeroing + scatter ----
    {
        for (int sp = bid; sp < NSPAN; sp += nblk) {
            __syncthreads();
            if (t < SPAN) sm.s.hcnt[t] = P.hc[sp * SPAN + t];
            __syncthreads();
            for (int off = 1; off < SPAN; off <<= 1) {
                int a = (t >= off && t < SPAN) ? sm.s.hcnt[t - off] : 0;
                __syncthreads();
                if (t < SPAN) sm.s.hcnt[t] += a;
                __syncthreads();
            }
            if (t < SPAN) {
                int excl = t ? sm.s.hcnt[t - 1] : 0;
                P.rank[sp * SPAN + t] = P.blocksum[sp] + excl;
            }
        }
        int ineed = mode ? itot : i0;
        float4 z = make_float4(0.f, 0.f, 0.f, 0.f);
        float4* hz = (float4*)P.h_sum;
        float4* fz = (float4*)P.fc_sum;
        int n4 = ineed * (MD / 4);
        for (int i = gtid; i < n4; i += gsize) { hz[i] = z; fz[i] = z; }
        for (int i = t; i < 2 * DCAP; i += NT) sm.s.hcnt[i] = 0;
        __syncthreads();
        for (int g = gtid; g < TWO_N; g += gsize) {
            int tree = g >> 16;
            int d = P.dep_a[g];
            if (d < DCAP) atomicAdd(&sm.s.hcnt[tree * DCAP + d], 1);
        }
        __syncthreads();
        for (int i = t; i < 2 * DCAP; i += NT) {
            int c = sm.s.hcnt[i];
            if (c > 0) {
                int idx = (i >= DCAP ? DMAX : 0) + (i & (DCAP - 1));
                sm.s.hbase[i] = P.offs[idx] + atomicAdd(&P.cur[idx], c);
            }
            sm.s.hcnt[i] = 0;
        }
        __syncthreads();
        for (int g = gtid; g < TWO_N; g += gsize) {
            int tree = g >> 16;
            int d = P.dep_a[g];
            if (d < DCAP) {
                int b = tree * DCAP + d;
                int pos = atomicAdd(&sm.s.hcnt[b], 1);
                P.order[sm.s.hbase[b] + pos] = g;
            } else {
                int idx = tree * DMAX + d;
                int pos = atomicAdd(&P.cur[idx], 1);
                P.order[P.offs[idx] + pos] = g;
            }
        }
    }
    gbarrier(P.bar, bid, nblk, gsz, ++ep, t);
    // barrier release writes back the zeroed state rows to the coherence point

    // ---- ladder ----
    if (mode) {
        int GT = P.maxd[22];
        for (int j = bid; j < GT; j += nblk) {
            int e = P.gtab[j];
            process_group(P, sm, e & 0xFFFFF, e >> 20, t, 0, 1);
        }
        gbarrier(P.bar, bid, nblk, gsz, ++ep, t);
    } else {
        for (int tree = 0; tree < 2; ++tree) {
            if (tree == 1) {
                int i1 = itot - i0;
                float4 z = make_float4(0.f, 0.f, 0.f, 0.f);
                float4* hz = (float4*)P.h_sum;
                float4* fz = (float4*)P.fc_sum;
                int n4 = i1 * (MD / 4);
                for (int i = gtid; i < n4; i += gsize) { hz[i] = z; fz[i] = z; }
                gbarrier(P.bar, bid, nblk, gsz, ++ep, t);
            }
            int rb = tree ? i0 : 0;
            int md = P.maxd[tree];
            for (int d = md; d >= 0; --d) {
                int n = P.cnt[tree * DMAX + d];
                int ng = (n + NB - 1) / NB;
                for (int grp = bid; grp < ng; grp += nblk) {
                    int st = P.offs[tree * DMAX + d] + grp * NB;
                    int cv = n - grp * NB; if (cv > NB) cv = NB;
                    process_group(P, sm, st, cv, t, rb, 0);
                }
                gbarrier(P.bar, bid, nblk, gsz, ++ep, t);
            }
        }
    }

    // ---- head ----
    if (bid == 0) head_body(P, sm, t);
}

extern "C" void kernel_launch(void* const* d_in, const int* in_sizes, int n_in,
                              void* d_out, int out_size, void* d_ws, size_t ws_size,
                              hipStream_t stream) {
    Params P;
    P.l_tokens = (const int*)d_in[0];
    P.l_parent = (const int*)d_in[1];
    P.r_tokens = (const int*)d_in[2];
    P.r_parent = (const int*)d_in[3];
    P.emb_W = (const float*)d_in[4];
    P.Wioux = (const float*)d_in[5];
    P.bioux = (const float*)d_in[6];
    P.Wiouh = (const float*)d_in[7];
    P.biouh = (const float*)d_in[8];
    P.Wfx   = (const float*)d_in[9];
    P.bfx   = (const float*)d_in[10];
    P.Wfh   = (const float*)d_in[11];
    P.bfh   = (const float*)d_in[12];
    P.Wh    = (const float*)d_in[13];
    P.bh    = (const float*)d_in[14];
    P.Wp    = (const float*)d_in[15];
    P.bp    = (const float*)d_in[16];
    P.out   = (float*)d_out;

    char* w = (char*)d_ws;
    auto alloc = [&](size_t bytes) {
        char* r = w;
        w += (bytes + 255) & ~(size_t)255;
        return r;
    };
    P.E_ioux   = (float*)alloc((size_t)VOCAB * G3 * 4);
    P.E_fx     = (float*)alloc((size_t)VOCAB * MD * 4);
    P.Wiouh_p  = (unsigned int*)alloc((size_t)(MD / 2) * G3 * 4);
    P.Wfh_p    = (unsigned int*)alloc((size_t)(MD / 2) * MD * 4);
    P.c_root   = (float*)alloc(2 * MD * 4);
    P.anc_a    = (int*)alloc((size_t)TWO_N * 4);
    P.dep_a    = (int*)alloc((size_t)TWO_N * 4);
    P.hc       = (int*)alloc((size_t)TWO_N * 4);
    P.pending  = (int*)alloc((size_t)TWO_N * 4);
    P.cnt      = (int*)alloc((size_t)2 * DMAX * 4);
    P.offs     = (int*)alloc((size_t)2 * DMAX * 4);
    P.cur      = (int*)alloc((size_t)2 * DMAX * 4);
    P.order    = (int*)alloc((size_t)TWO_N * 4);
    P.rank     = (int*)alloc((size_t)TWO_N * 4);
    P.blocksum = (int*)alloc((size_t)NSPAN * 4);
    P.gtab     = (int*)alloc((size_t)(TWO_N / NB + 2 * DMAX + 256) * 4);
    P.dbase    = (int*)alloc((size_t)DMAX * 4);
    P.maxd     = (int*)alloc(256);
    P.bar      = (int*)alloc((size_t)(MAXBLK * SLOTSTRIDE + NGRP * 32 + 64) * 4);
    // doubling scratch aliases buffers that are only written later
    P.anc_b = P.order;
    P.dep_b = P.rank;

    size_t used = (size_t)(w - (char*)d_ws);
    size_t remain = (ws_size > used) ? (ws_size - used) : 0;
    size_t cap = remain / ((size_t)2 * MD * 4);
    if (cap > (size_t)TWO_N) cap = TWO_N;
    P.cap_rows = (int)cap;
    P.h_sum  = (float*)w;
    P.fc_sum = P.h_sum + cap * MD;

    hipMemsetAsync(P.bar, 0, (size_t)(MAXBLK * SLOTSTRIDE + NGRP * 32 + 64) * 4,
                   stream);

    int bpc = 1;
    hipOccupancyMaxActiveBlocksPerMultiprocessor(&bpc, (const void*)fused_kernel,
                                                 NT, 0);
    if (bpc < 1) bpc = 1;
    if (bpc > 8) bpc = 8;
    int nblk = 256 * bpc;            // multiple of NGRP(32)

    fused_kernel<<<dim3(nblk), dim3(NT), 0, stream>>>(P);
}

// Round 18
// 3703.204 us; speedup vs baseline: 1.1313x; 1.1313x over previous
//
#include <hip/hip_runtime.h>
#include <math.h>

#define NN 65536
#define TWO_N (2 * NN)
#define VOCAB 1000
#define MD 256
#define G3 768
#define DMAX 65536
#define DCAP 128
#define NB 4
#define NT 256
#define NGRP 32
#define NSPAN 1024
#define SPAN 128
#define SLOTSTRIDE 16
#define MAXBLK 2048

struct Params {
    const int* l_tokens; const int* l_parent;
    const int* r_tokens; const int* r_parent;
    const float* emb_W;
    const float* Wioux; const float* bioux;
    const float* Wiouh; const float* biouh;
    const float* Wfx;   const float* bfx;
    const float* Wfh;   const float* bfh;
    const float* Wh;    const float* bh;
    const float* Wp;    const float* bp;
    float* out;
    // workspace
    float* E_ioux;   // [VOCAB][768]
    float* E_fx;     // [VOCAB][256]
    unsigned int* Wiouh_p;  // [128][768] packed bf16 pairs (k,k+1)
    unsigned int* Wfh_p;    // [128][256] packed bf16 pairs
    float* h_sum;    // [cap_rows][256]
    float* fc_sum;   // [cap_rows][256]
    float* c_root;   // [2][256]
    int* anc_a; int* anc_b; int* dep_a; int* dep_b;  // [2N] (b aliased)
    int* hc;                                          // [2N]
    int* pending;                                     // [2N] dataflow counters
    int* rank;                                        // [2N]
    int* blocksum;                                    // [NSPAN]
    int* cnt; int* offs; int* cur;                    // [2*DMAX]
    int* order;                                        // [2N]
    int* gtab;                                         // flat group table
    int* dbase;                                        // [DMAX] per-depth group base
    int* maxd;   // [0..1]=maxd, +2 flags, 20=mode, 21=Itot, 22=GT
    int* bar;
    int cap_rows;
};

union SMem {
    struct { float es[4][MD]; } e;
    struct {
        float hls[NB][MD];
        int nid[NB]; int row[NB]; int prow[NB]; int tok[NB]; int ptok[NB];
        int pgid[NB];
    } w;
    struct { int hcnt[2 * DCAP]; int hbase[2 * DCAP]; int hmax2[2]; } s;
    struct { float vec[2 * MD]; float red[2][NT]; } h;
};

__device__ __forceinline__ float sigmoidf_(float x) {
    return 1.0f / (1.0f + __expf(-x));
}
__device__ __forceinline__ float tanhf_(float x) {
    float ex = __expf(2.0f * x);
    return 1.0f - 2.0f / (ex + 1.0f);
}
__device__ __forceinline__ unsigned int bf16rne_(float x) {
    unsigned int b = __float_as_uint(x);
    return (b + 0x7FFFu + ((b >> 16) & 1u)) >> 16;
}
__device__ __forceinline__ float bflo_(unsigned int w) {
    return __uint_as_float(w << 16);
}
__device__ __forceinline__ float bfhi_(unsigned int w) {
    return __uint_as_float(w & 0xFFFF0000u);
}

__device__ __forceinline__ int aload_(int* p) {
    return __hip_atomic_load(p, __ATOMIC_RELAXED, __HIP_MEMORY_SCOPE_AGENT);
}
// coherence-point float load (bypasses potentially-stale L1/L2) for dataflow
__device__ __forceinline__ float loadf_coh(const float* p, int df) {
    if (df) return __hip_atomic_load((float*)p, __ATOMIC_RELAXED,
                                     __HIP_MEMORY_SCOPE_AGENT);
    return *p;
}

// ---- slot barrier: store arrivals, block-0 sweep, group release ----
__device__ void gbarrier(int* bar, int bid, int nblk, int gsz, int ep, int t) {
    __syncthreads();
    int* relw = bar + MAXBLK * SLOTSTRIDE;
    if (t == 0) {
        __builtin_amdgcn_fence(__ATOMIC_RELEASE, "agent");
        __hip_atomic_store(bar + bid * SLOTSTRIDE, ep, __ATOMIC_RELAXED,
                           __HIP_MEMORY_SCOPE_AGENT);
    }
    if (bid == 0) {
        for (int s = t; s < nblk; s += NT) {
            while (aload_(bar + s * SLOTSTRIDE) < ep) __builtin_amdgcn_s_sleep(1);
        }
        __builtin_amdgcn_fence(__ATOMIC_ACQUIRE, "agent");
        __syncthreads();
        if (t < NGRP) {
            __builtin_amdgcn_fence(__ATOMIC_RELEASE, "agent");
            __hip_atomic_store(relw + t * 32, ep, __ATOMIC_RELAXED,
                               __HIP_MEMORY_SCOPE_AGENT);
        }
    } else {
        if (t == 0) {
            int g = bid / gsz; if (g >= NGRP) g = NGRP - 1;
            while (aload_(relw + g * 32) < ep) __builtin_amdgcn_s_sleep(2);
            __builtin_amdgcn_fence(__ATOMIC_ACQUIRE, "agent");
        }
    }
    __syncthreads();
}

// processes NB nodes of ONE tree; df=1 -> dataflow (spin on pending, bypass state loads)
__device__ void process_group(const Params& P, SMem& sm, int base, int cntv,
                              int t, int rowbase, int df) {
    __syncthreads();
    if (t < NB) {
        int g = -1, row = -1, prow = 0, tok = 0, ptok = 0, pgid = 0;
        if (t < cntv) {
            g = P.order[base + t];
            int tree = g >> 16, i = g & (NN - 1);
            const int* toks = tree ? P.r_tokens : P.l_tokens;
            const int* pars = tree ? P.r_parent : P.l_parent;
            tok = toks[i];
            int pl = pars[i];
            ptok = toks[pl];
            pgid = (tree << 16) | pl;
            if (P.hc[g]) row = P.rank[g] - rowbase;      // leaf -> -1 (zero state)
            prow = P.rank[pgid] - rowbase;               // parent always internal
        }
        sm.w.nid[t] = g; sm.w.row[t] = row; sm.w.prow[t] = prow;
        sm.w.tok[t] = tok; sm.w.ptok[t] = ptok; sm.w.pgid[t] = pgid;
        if (df && g >= 0) {
            while (aload_(&P.pending[g]) != 0) __builtin_amdgcn_s_sleep(8);
        }
    }
    __syncthreads();
    #pragma unroll
    for (int nb = 0; nb < NB; ++nb) {
        int r = sm.w.row[nb];
        sm.w.hls[nb][t] = (r >= 0)
            ? loadf_coh(&P.h_sum[(size_t)r * MD + t], df) : 0.0f;
    }
    __syncthreads();

    // ---- iou = E_ioux[tok] + h_sum @ Wiouh + biouh (bf16 weights) ----
    float ai[NB], ao[NB], au[NB];
    #pragma unroll
    for (int nb = 0; nb < NB; ++nb) { ai[nb] = 0.f; ao[nb] = 0.f; au[nb] = 0.f; }
    const unsigned int* Wp = P.Wiouh_p;
    #pragma unroll 4
    for (int k = 0; k < MD; k += 4) {
        int r0 = (k >> 1) * G3 + t;
        unsigned int a01 = Wp[r0],       a23 = Wp[r0 + G3];
        unsigned int b01 = Wp[r0 + 256], b23 = Wp[r0 + G3 + 256];
        unsigned int c01 = Wp[r0 + 512], c23 = Wp[r0 + G3 + 512];
        float wi0 = bflo_(a01), wi1 = bfhi_(a01), wi2 = bflo_(a23), wi3 = bfhi_(a23);
        float wo0 = bflo_(b01), wo1 = bfhi_(b01), wo2 = bflo_(b23), wo3 = bfhi_(b23);
        float wu0 = bflo_(c01), wu1 = bfhi_(c01), wu2 = bflo_(c23), wu3 = bfhi_(c23);
        #pragma unroll
        for (int nb = 0; nb < NB; ++nb) {
            float4 hv = *(const float4*)&sm.w.hls[nb][k];
            ai[nb] += wi0 * hv.x; ai[nb] += wi1 * hv.y; ai[nb] += wi2 * hv.z; ai[nb] += wi3 * hv.w;
            ao[nb] += wo0 * hv.x; ao[nb] += wo1 * hv.y; ao[nb] += wo2 * hv.z; ao[nb] += wo3 * hv.w;
            au[nb] += wu0 * hv.x; au[nb] += wu1 * hv.y; au[nb] += wu2 * hv.z; au[nb] += wu3 * hv.w;
        }
    }

    // ---- gates, c, h ----
    float cv[NB];
    float b_i = P.biouh[t], b_o = P.biouh[256 + t], b_u = P.biouh[512 + t];
    __syncthreads();
    #pragma unroll
    for (int nb = 0; nb < NB; ++nb) {
        int g = sm.w.nid[nb];
        float hval = 0.0f, cval = 0.0f;
        if (g >= 0) {
            const float* Ei = P.E_ioux + (size_t)sm.w.tok[nb] * G3;
            float ig = Ei[t] + ai[nb] + b_i;
            float og = Ei[256 + t] + ao[nb] + b_o;
            float ug = Ei[512 + t] + au[nb] + b_u;
            int r = sm.w.row[nb];
            float fcv = (r >= 0)
                ? loadf_coh(&P.fc_sum[(size_t)r * MD + t], df) : 0.0f;
            cval = sigmoidf_(ig) * tanhf_(ug) + fcv;
            hval = sigmoidf_(og) * tanhf_(cval);
        }
        cv[nb] = cval;
        sm.w.hls[nb][t] = hval;
    }
    __syncthreads();

    // ---- f = sigmoid(h @ Wfh + bfh + E_fx[ptok]) ; scatter to parent ----
    float af[NB];
    #pragma unroll
    for (int nb = 0; nb < NB; ++nb) af[nb] = 0.f;
    const unsigned int* Wfp = P.Wfh_p;
    #pragma unroll 4
    for (int k = 0; k < MD; k += 4) {
        int r0 = (k >> 1) * MD + t;
        unsigned int f01 = Wfp[r0], f23 = Wfp[r0 + MD];
        float wf0 = bflo_(f01), wf1 = bfhi_(f01), wf2 = bflo_(f23), wf3 = bfhi_(f23);
        #pragma unroll
        for (int nb = 0; nb < NB; ++nb) {
            float4 hv = *(const float4*)&sm.w.hls[nb][k];
            af[nb] += wf0 * hv.x; af[nb] += wf1 * hv.y; af[nb] += wf2 * hv.z; af[nb] += wf3 * hv.w;
        }
    }
    float b_f = P.bfh[t];
    #pragma unroll
    for (int nb = 0; nb < NB; ++nb) {
        int g = sm.w.nid[nb];
        if (g < 0) continue;
        int i = g & (NN - 1);
        if (i == 0) {
            P.c_root[(g >> 16) * MD + t] = cv[nb];
        } else {
            float f = sigmoidf_(af[nb] + b_f + P.E_fx[(size_t)sm.w.ptok[nb] * MD + t]);
            int p = sm.w.prow[nb];
            atomicAdd(&P.h_sum[(size_t)p * MD + t], sm.w.hls[nb][t]);
            atomicAdd(&P.fc_sum[(size_t)p * MD + t], f * cv[nb]);
        }
    }
    if (df) {
        __syncthreads();   // drains every wave's vmcnt -> all atomics complete
        if (t < NB) {
            int g = sm.w.nid[t];
            if (g >= 0 && (g & (NN - 1)) != 0) {
                __builtin_amdgcn_fence(__ATOMIC_RELEASE, "agent");
                __hip_atomic_fetch_add(&P.pending[sm.w.pgid[t]], -1,
                                       __ATOMIC_RELAXED, __HIP_MEMORY_SCOPE_AGENT);
            }
        }
    }
}

__device__ void etab_body(const Params& P, SMem& sm, int t, int bid, int nblk) {
    for (int v0 = bid * 4; v0 < VOCAB; v0 += nblk * 4) {
        __syncthreads();
        #pragma unroll
        for (int r = 0; r < 4; ++r)
            sm.e.es[r][t] = (v0 + r < VOCAB) ? P.emb_W[(size_t)(v0 + r) * MD + t] : 0.f;
        __syncthreads();
        float a0[4] = {0.f,0.f,0.f,0.f}, a1[4] = {0.f,0.f,0.f,0.f};
        float a2[4] = {0.f,0.f,0.f,0.f}, a3[4] = {0.f,0.f,0.f,0.f};
        for (int k = 0; k < MD; ++k) {
            float wi = P.Wioux[k * G3 + t];
            float wo = P.Wioux[k * G3 + 256 + t];
            float wu = P.Wioux[k * G3 + 512 + t];
            float wf = P.Wfx[k * MD + t];
            #pragma unroll
            for (int r = 0; r < 4; ++r) {
                float e = sm.e.es[r][k];
                a0[r] += wi * e; a1[r] += wo * e; a2[r] += wu * e; a3[r] += wf * e;
            }
        }
        float bi = P.bioux[t], bo = P.bioux[256 + t], bu = P.bioux[512 + t], bf = P.bfx[t];
        for (int r = 0; r < 4; ++r) {
            if (v0 + r < VOCAB) {
                P.E_ioux[(size_t)(v0 + r) * G3 + t]       = a0[r] + bi;
                P.E_ioux[(size_t)(v0 + r) * G3 + 256 + t] = a1[r] + bo;
                P.E_ioux[(size_t)(v0 + r) * G3 + 512 + t] = a2[r] + bu;
                P.E_fx[(size_t)(v0 + r) * MD + t]         = a3[r] + bf;
            }
        }
        __syncthreads();
    }
}

__device__ void head_body(const Params& P, SMem& sm, int t) {
    float cl = P.c_root[t], cr = P.c_root[MD + t];
    sm.h.vec[t] = cl * cr;
    sm.h.vec[MD + t] = fabsf(cl - cr);
    __syncthreads();
    float acc = 0.f;
    for (int j = 0; j < 2 * MD; ++j) acc += sm.h.vec[j] * P.Wh[(size_t)j * MD + t];
    float hid = sigmoidf_(acc + P.bh[t]);
    sm.h.red[0][t] = hid * P.Wp[t * 2 + 0];
    sm.h.red[1][t] = hid * P.Wp[t * 2 + 1];
    __syncthreads();
    for (int s = 128; s > 0; s >>= 1) {
        if (t < s) {
            sm.h.red[0][t] += sm.h.red[0][t + s];
            sm.h.red[1][t] += sm.h.red[1][t + s];
        }
        __syncthreads();
    }
    if (t == 0) {
        float l0 = sm.h.red[0][0] + P.bp[0];
        float l1 = sm.h.red[1][0] + P.bp[1];
        float mx = fmaxf(l0, l1);
        float e0 = __expf(l0 - mx), e1 = __expf(l1 - mx);
        float inv = 1.0f / (e0 + e1);
        P.out[0] = e0 * inv;
        P.out[1] = e1 * inv;
    }
}

// =======================================================================
// Persistent fused kernel: dataflow ladder, NB=4, deep-unroll weight loops.
// =======================================================================
__global__ __launch_bounds__(NT, 4) void fused_kernel(Params P) {
    __shared__ SMem sm;
    const int t = threadIdx.x;
    const int bid = blockIdx.x;
    const int nblk = gridDim.x;
    const int gsz = nblk / NGRP;
    const int gsize = nblk * NT;
    const int gtid = bid * NT + t;
    int* flags = P.maxd + 2;
    int ep = 0;

    // ---- A0: zero flags/counters/hc/pending + weight compress + E tables ----
    for (int i = gtid; i < TWO_N; i += gsize) { P.hc[i] = 0; P.pending[i] = 0; }
    for (int i = gtid; i < 2 * DMAX; i += gsize) { P.cnt[i] = 0; P.cur[i] = 0; }
    if (gtid < 2) P.maxd[gtid] = 0;
    if (gtid >= 2 && gtid < 24) flags[gtid - 2] = 0;
    for (int i = gtid; i < (MD / 2) * G3; i += gsize) {
        int kk = i / G3, n = i - kk * G3;
        float x0 = P.Wiouh[(size_t)(2 * kk) * G3 + n];
        float x1 = P.Wiouh[(size_t)(2 * kk + 1) * G3 + n];
        P.Wiouh_p[i] = bf16rne_(x0) | (bf16rne_(x1) << 16);
    }
    for (int i = gtid; i < (MD / 2) * MD; i += gsize) {
        int kk = i >> 8, n = i & (MD - 1);
        float x0 = P.Wfh[(size_t)(2 * kk) * MD + n];
        float x1 = P.Wfh[(size_t)(2 * kk + 1) * MD + n];
        P.Wfh_p[i] = bf16rne_(x0) | (bf16rne_(x1) << 16);
    }
    etab_body(P, sm, t, bid, nblk);
    gbarrier(P.bar, bid, nblk, gsz, ++ep, t);

    // ---- A1: anc/dep init + has-child flags + child counts ----
    for (int g = gtid; g < TWO_N; g += gsize) {
        int tree = g >> 16, i = g & (NN - 1);
        if (i == 0) { P.anc_a[g] = g; P.dep_a[g] = 0; }
        else {
            const int* par = tree ? P.r_parent : P.l_parent;
            int pg = (tree << 16) | par[i];
            P.anc_a[g] = pg;
            P.dep_a[g] = 1;
            P.hc[pg] = 1;
            atomicAdd(&P.pending[pg], 1);
        }
    }
    gbarrier(P.bar, bid, nblk, gsz, ++ep, t);

    // ---- C: pointer doubling with early exit ----
    {
        int* pa = P.anc_a; int* pd = P.dep_a; int* qa = P.anc_b; int* qd = P.dep_b;
        for (int it = 0; it < 16; ++it) {
            int changed = 0;
            for (int g = gtid; g < TWO_N; g += gsize) {
                int a = pa[g];
                int da = pd[a];
                qd[g] = pd[g] + da;
                qa[g] = pa[a];
                changed |= (da != 0);
            }
            if (changed) flags[it] = 1;
            gbarrier(P.bar, bid, nblk, gsz, ++ep, t);
            int* tmp = pa; pa = qa; qa = tmp;
            tmp = pd; pd = qd; qd = tmp;
            if (flags[it] == 0) break;
        }
        if (pd != P.dep_a) {
            for (int g = gtid; g < TWO_N; g += gsize) P.dep_a[g] = pd[g];
            gbarrier(P.bar, bid, nblk, gsz, ++ep, t);
        }
    }

    // ---- S1: depth hist + per-span hc sums ----
    {
        for (int i = t; i < 2 * DCAP; i += NT) sm.s.hcnt[i] = 0;
        if (t < 2) sm.s.hmax2[t] = 0;
        __syncthreads();
        for (int g = gtid; g < TWO_N; g += gsize) {
            int tree = g >> 16;
            int d = P.dep_a[g];
            if (d < DCAP) {
                atomicAdd(&sm.s.hcnt[tree * DCAP + d], 1);
                atomicMax(&sm.s.hmax2[tree], d);
            } else {
                atomicAdd(&P.cnt[tree * DMAX + d], 1);
                atomicMax(&P.maxd[tree], d);
            }
        }
        __syncthreads();
        for (int i = t; i < 2 * DCAP; i += NT) {
            int c = sm.s.hcnt[i];
            if (c > 0) atomicAdd(&P.cnt[(i >= DCAP ? DMAX : 0) + (i & (DCAP - 1))], c);
        }
        if (t < 2) atomicMax(&P.maxd[t], sm.s.hmax2[t]);
        for (int sp = bid; sp < NSPAN; sp += nblk) {
            __syncthreads();
            if (t == 0) sm.s.hbase[0] = 0;
            __syncthreads();
            if (t < SPAN && P.hc[sp * SPAN + t]) atomicAdd(&sm.s.hbase[0], 1);
            __syncthreads();
            if (t == 0) P.blocksum[sp] = sm.s.hbase[0];
        }
    }
    gbarrier(P.bar, bid, nblk, gsz, ++ep, t);

    // ---- S2 (block 0): scans; Itot; mode; offs prefix; group table ----
    if (bid == 0) {
        int4 v = ((const int4*)P.blocksum)[t];
        int s = v.x + v.y + v.z + v.w;
        sm.s.hcnt[t] = s;
        __syncthreads();
        for (int off = 1; off < NT; off <<= 1) {
            int a = (t >= off) ? sm.s.hcnt[t - off] : 0;
            __syncthreads();
            sm.s.hcnt[t] += a;
            __syncthreads();
        }
        int excl = t ? sm.s.hcnt[t - 1] : 0;
        int4 r;
        r.x = excl; r.y = r.x + v.x; r.z = r.y + v.y; r.w = r.z + v.z;
        ((int4*)P.blocksum)[t] = r;
        if (t == NT - 1) {
            int itot = sm.s.hcnt[NT - 1];
            P.maxd[21] = itot;
            P.maxd[20] = (itot <= P.cap_rows) ? 1 : 0;
        }
        __syncthreads();
        if (t < 2) {
            int tree = t;
            int run = tree * NN;
            int md = P.maxd[tree];
            for (int d = 0; d <= md; ++d) {
                P.offs[tree * DMAX + d] = run;
                run += P.cnt[tree * DMAX + d];
            }
        }
        __syncthreads();
        int md0 = P.maxd[0], md1 = P.maxd[1];
        int md = md0 > md1 ? md0 : md1;
        if (t == 0) {
            int j = 0;
            for (int d = md; d >= 0; --d) {
                P.dbase[d] = j;
                int n0 = (d <= md0) ? P.cnt[d] : 0;
                int n1 = (d <= md1) ? P.cnt[DMAX + d] : 0;
                j += (n0 + NB - 1) / NB + (n1 + NB - 1) / NB;
            }
            P.maxd[22] = j;   // GT
        }
        __syncthreads();
        for (int d = t; d <= md; d += NT) {
            int j = P.dbase[d];
            for (int tr = 0; tr < 2; ++tr) {
                int mdt = tr ? md1 : md0;
                int n = (d <= mdt) ? P.cnt[tr * DMAX + d] : 0;
                int st = P.offs[tr * DMAX + d];
                for (int b = 0; b < n; b += NB) {
                    int cv = n - b; if (cv > NB) cv = NB;
                    P.gtab[j++] = (st + b) | (cv << 20);
                }
            }
        }
    }
    gbarrier(P.bar, bid, nblk, gsz, ++ep, t);

    int mode = P.maxd[20];
    int itot = P.maxd[21];
    int i0 = P.blocksum[NSPAN / 2];

    // ---- S3: rank writes + state zeroing + scatter ----
    {
        for (int sp = bid; sp < NSPAN; sp += nblk) {
            __syncthreads();
            if (t < SPAN) sm.s.hcnt[t] = P.hc[sp * SPAN + t];
            __syncthreads();
            for (int off = 1; off < SPAN; off <<= 1) {
                int a = (t >= off && t < SPAN) ? sm.s.hcnt[t - off] : 0;
                __syncthreads();
                if (t < SPAN) sm.s.hcnt[t] += a;
                __syncthreads();
            }
            if (t < SPAN) {
                int excl = t ? sm.s.hcnt[t - 1] : 0;
                P.rank[sp * SPAN + t] = P.blocksum[sp] + excl;
            }
        }
        int ineed = mode ? itot : i0;
        float4 z = make_float4(0.f, 0.f, 0.f, 0.f);
        float4* hz = (float4*)P.h_sum;
        float4* fz = (float4*)P.fc_sum;
        int n4 = ineed * (MD / 4);
        for (int i = gtid; i < n4; i += gsize) { hz[i] = z; fz[i] = z; }
        for (int i = t; i < 2 * DCAP; i += NT) sm.s.hcnt[i] = 0;
        __syncthreads();
        for (int g = gtid; g < TWO_N; g += gsize) {
            int tree = g >> 16;
            int d = P.dep_a[g];
            if (d < DCAP) atomicAdd(&sm.s.hcnt[tree * DCAP + d], 1);
        }
        __syncthreads();
        for (int i = t; i < 2 * DCAP; i += NT) {
            int c = sm.s.hcnt[i];
            if (c > 0) {
                int idx = (i >= DCAP ? DMAX : 0) + (i & (DCAP - 1));
                sm.s.hbase[i] = P.offs[idx] + atomicAdd(&P.cur[idx], c);
            }
            sm.s.hcnt[i] = 0;
        }
        __syncthreads();
        for (int g = gtid; g < TWO_N; g += gsize) {
            int tree = g >> 16;
            int d = P.dep_a[g];
            if (d < DCAP) {
                int b = tree * DCAP + d;
                int pos = atomicAdd(&sm.s.hcnt[b], 1);
                P.order[sm.s.hbase[b] + pos] = g;
            } else {
                int idx = tree * DMAX + d;
                int pos = atomicAdd(&P.cur[idx], 1);
                P.order[P.offs[idx] + pos] = g;
            }
        }
    }
    gbarrier(P.bar, bid, nblk, gsz, ++ep, t);
    // barrier release writes back the zeroed state rows to the coherence point

    // ---- ladder ----
    if (mode) {
        int GT = P.maxd[22];
        for (int j = bid; j < GT; j += nblk) {
            int e = P.gtab[j];
            process_group(P, sm, e & 0xFFFFF, e >> 20, t, 0, 1);
        }
        gbarrier(P.bar, bid, nblk, gsz, ++ep, t);
    } else {
        for (int tree = 0; tree < 2; ++tree) {
            if (tree == 1) {
                int i1 = itot - i0;
                float4 z = make_float4(0.f, 0.f, 0.f, 0.f);
                float4* hz = (float4*)P.h_sum;
                float4* fz = (float4*)P.fc_sum;
                int n4 = i1 * (MD / 4);
                for (int i = gtid; i < n4; i += gsize) { hz[i] = z; fz[i] = z; }
                gbarrier(P.bar, bid, nblk, gsz, ++ep, t);
            }
            int rb = tree ? i0 : 0;
            int md = P.maxd[tree];
            for (int d = md; d >= 0; --d) {
                int n = P.cnt[tree * DMAX + d];
                int ng = (n + NB - 1) / NB;
                for (int grp = bid; grp < ng; grp += nblk) {
                    int st = P.offs[tree * DMAX + d] + grp * NB;
                    int cv = n - grp * NB; if (cv > NB) cv = NB;
                    process_group(P, sm, st, cv, t, rb, 0);
                }
                gbarrier(P.bar, bid, nblk, gsz, ++ep, t);
            }
        }
    }

    // ---- head ----
    if (bid == 0) head_body(P, sm, t);
}

extern "C" void kernel_launch(void* const* d_in, const int* in_sizes, int n_in,
                              void* d_out, int out_size, void* d_ws, size_t ws_size,
                              hipStream_t stream) {
    Params P;
    P.l_tokens = (const int*)d_in[0];
    P.l_parent = (const int*)d_in[1];
    P.r_tokens = (const int*)d_in[2];
    P.r_parent = (const int*)d_in[3];
    P.emb_W = (const float*)d_in[4];
    P.Wioux = (const float*)d_in[5];
    P.bioux = (const float*)d_in[6];
    P.Wiouh = (const float*)d_in[7];
    P.biouh = (const float*)d_in[8];
    P.Wfx   = (const float*)d_in[9];
    P.bfx   = (const float*)d_in[10];
    P.Wfh   = (const float*)d_in[11];
    P.bfh   = (const float*)d_in[12];
    P.Wh    = (const float*)d_in[13];
    P.bh    = (const float*)d_in[14];
    P.Wp    = (const float*)d_in[15];
    P.bp    = (const float*)d_in[16];
    P.out   = (float*)d_out;

    char* w = (char*)d_ws;
    auto alloc = [&](size_t bytes) {
        char* r = w;
        w += (bytes + 255) & ~(size_t)255;
        return r;
    };
    P.E_ioux   = (float*)alloc((size_t)VOCAB * G3 * 4);
    P.E_fx     = (float*)alloc((size_t)VOCAB * MD * 4);
    P.Wiouh_p  = (unsigned int*)alloc((size_t)(MD / 2) * G3 * 4);
    P.Wfh_p    = (unsigned int*)alloc((size_t)(MD / 2) * MD * 4);
    P.c_root   = (float*)alloc(2 * MD * 4);
    P.anc_a    = (int*)alloc((size_t)TWO_N * 4);
    P.dep_a    = (int*)alloc((size_t)TWO_N * 4);
    P.hc       = (int*)alloc((size_t)TWO_N * 4);
    P.pending  = (int*)alloc((size_t)TWO_N * 4);
    P.cnt      = (int*)alloc((size_t)2 * DMAX * 4);
    P.offs     = (int*)alloc((size_t)2 * DMAX * 4);
    P.cur      = (int*)alloc((size_t)2 * DMAX * 4);
    P.order    = (int*)alloc((size_t)TWO_N * 4);
    P.rank     = (int*)alloc((size_t)TWO_N * 4);
    P.blocksum = (int*)alloc((size_t)NSPAN * 4);
    P.gtab     = (int*)alloc((size_t)(TWO_N / NB + 2 * DMAX + 256) * 4);
    P.dbase    = (int*)alloc((size_t)DMAX * 4);
    P.maxd     = (int*)alloc(256);
    P.bar      = (int*)alloc((size_t)(MAXBLK * SLOTSTRIDE + NGRP * 32 + 64) * 4);
    // doubling scratch aliases buffers that are only written later
    P.anc_b = P.order;
    P.dep_b = P.rank;

    size_t used = (size_t)(w - (char*)d_ws);
    size_t remain = (ws_size > used) ? (ws_size - used) : 0;
    size_t cap = remain / ((size_t)2 * MD * 4);
    if (cap > (size_t)TWO_N) cap = TWO_N;
    P.cap_rows = (int)cap;
    P.h_sum  = (float*)w;
    P.fc_sum = P.h_sum + cap * MD;

    hipMemsetAsync(P.bar, 0, (size_t)(MAXBLK * SLOTSTRIDE + NGRP * 32 + 64) * 4,
                   stream);

    int bpc = 1;
    hipOccupancyMaxActiveBlocksPerMultiprocessor(&bpc, (const void*)fused_kernel,
                                                 NT, 0);
    if (bpc < 1) bpc = 1;
    if (bpc > 8) bpc = 8;
    int nblk = 256 * bpc;            // multiple of NGRP(32)

    fused_kernel<<<dim3(nblk), dim3(NT), 0, stream>>>(P);
}